// Round 3
// baseline (426.886 us; speedup 1.0000x reference)
//
#include <hip/hip_runtime.h>

#define NN     2048
#define DIM    512
#define NH     8
#define HD     64
#define NE     32768
#define EPAD   32832
#define CHUNKS 4
#define CHSZ   (NN/CHUNKS)      /* 512 keys per chunk */
#define NJT    (CHSZ/64)        /* 8 key-tiles of 64 per chunk */
#define LOG2E  1.4426950408889634f

typedef __attribute__((ext_vector_type(8))) short bf16x8;
typedef __attribute__((ext_vector_type(4))) float f32x4;
typedef __attribute__((ext_vector_type(4))) unsigned int u32x4;

#define MFMA(a,b,c) __builtin_amdgcn_mfma_f32_16x16x32_bf16((a),(b),(c),0,0,0)

__device__ __forceinline__ float bf2f(unsigned int u16){
  union { unsigned int i; float f; } v; v.i = u16 << 16; return v.f;
}
__device__ __forceinline__ unsigned short f2bf(float f){
  union { float ff; unsigned int i; } v; v.ff = f;
  return (unsigned short)((v.i + 0x7fffu + ((v.i >> 16) & 1u)) >> 16);
}

// ------- fp32 -> bf16 staging: node_feat -> Xb, edge_feat -> pEF (pad rows NE..EPAD-1 = 0),
// ------- edge_weight -> pEW (64 rows, rows 40..63 = 0). One 8-elem group per thread.
__global__ __launch_bounds__(256) void cvt_k(
    const float* __restrict__ X, const float* __restrict__ ef, const float* __restrict__ ew,
    unsigned short* __restrict__ Xb, unsigned short* __restrict__ pEF, unsigned short* __restrict__ pEW)
{
  long g = (long)blockIdx.x*256 + threadIdx.x;   // 8-element group index
  const long GX = (long)NN*DIM/8;                // 131072 groups
  const long GE = (long)EPAD*8;                  // 262656 groups
  const float* src; unsigned short* dst; long off, lim8;
  if (g < GX){ src = X;  dst = Xb;  off = g;        lim8 = GX; }
  else if (g < GX+GE){ src = ef; dst = pEF; off = g-GX; lim8 = (long)NE*8; }
  else { off = g-GX-GE; if (off >= 512) return; src = ew; dst = pEW; lim8 = 320; }
  unsigned short o[8];
  if (off < lim8){
    #pragma unroll
    for (int i=0;i<8;i++) o[i] = f2bf(src[off*8+i]);
  } else {
    #pragma unroll
    for (int i=0;i<8;i++) o[i] = 0;
  }
  *(uint4*)(dst + off*8) = *(const uint4*)o;
}

// ---------------- transpose + convert four 512x512 fp32 weight matrices -> bf16 ----------------
__global__ __launch_bounds__(256) void transpose512(
    const float* __restrict__ a0, const float* __restrict__ a1,
    const float* __restrict__ a2, const float* __restrict__ a3,
    unsigned short* __restrict__ out)
{
  __shared__ unsigned short tile[32][33];
  const float* src = blockIdx.z==0 ? a0 : blockIdx.z==1 ? a1 : blockIdx.z==2 ? a2 : a3;
  unsigned short* dst = out + (size_t)blockIdx.z*DIM*DIM;
  int bx = blockIdx.x*32, by = blockIdx.y*32;
  int tx = threadIdx.x, ty = threadIdx.y;
  #pragma unroll
  for (int i=0;i<32;i+=8) tile[ty+i][tx] = f2bf(src[(size_t)(by+ty+i)*DIM + bx+tx]);
  __syncthreads();
  #pragma unroll
  for (int i=0;i<32;i+=8) dst[(size_t)(bx+ty+i)*DIM + by+tx] = tile[tx][ty+i];
}

// ---------------- C[M][N] = A1[M][K] * A2[N][K]^T + bias(fp32) ----------------
__global__ __launch_bounds__(256) void gemm_bt(
    const unsigned short* __restrict__ A1, const unsigned short* __restrict__ A2,
    const float* __restrict__ bias, unsigned short* __restrict__ C, float* __restrict__ Cf,
    int M, int N, int K, int bias_row)
{
  int lane = threadIdx.x & 63, w = threadIdx.x >> 6;
  int quad = lane >> 4, low = lane & 15;
  int m0 = blockIdx.y*64 + w*16;
  int n0 = blockIdx.x*32;
  f32x4 acc[2];
  acc[0] = (f32x4){0.f,0.f,0.f,0.f};
  acc[1] = (f32x4){0.f,0.f,0.f,0.f};
  for (int k0=0; k0<K; k0+=32){
    bf16x8 a = *(const bf16x8*)(A1 + (size_t)(m0+low)*K + k0 + quad*8);
    #pragma unroll
    for (int t=0;t<2;t++){
      bf16x8 b = *(const bf16x8*)(A2 + (size_t)(n0+16*t+low)*K + k0 + quad*8);
      acc[t] = MFMA(a, b, acc[t]);
    }
  }
  #pragma unroll
  for (int t=0;t<2;t++){
    #pragma unroll
    for (int r=0;r<4;r++){
      int row = m0 + quad*4 + r;
      int col = n0 + 16*t + low;
      float v = acc[t][r];
      if (bias) v += bias[bias_row ? row : col];
      if (Cf) Cf[(size_t)row*N + col] = v;
      else    C [(size_t)row*N + col] = f2bf(v);
    }
  }
}

// ---------------- dedicated bias-gather kernel ----------------
// bias[n][m][h] (bf16) = sp_table[dist][h] + sum_l T2[sp_l][l*8+h], mask -> -1e30.
// One pair per thread; 5 independent 16B gathers; no barriers after init; max occupancy.
// Streams (dist/mask/sp) are nontemporal so they don't evict T2 from L2.
__global__ __launch_bounds__(256) void bias_k(
    const unsigned short* __restrict__ T2, const float* __restrict__ spb,
    const int* __restrict__ dist, const int* __restrict__ sp, const int* __restrict__ maskp,
    unsigned short* __restrict__ biasB)
{
  __shared__ float sptab[48];
  if (threadIdx.x < 48) sptab[threadIdx.x] = spb[threadIdx.x];
  __syncthreads();
  long pix = (long)blockIdx.x*256 + threadIdx.x;   // n*NN + m, grid covers NN*NN exactly
  int dd = __builtin_nontemporal_load(dist + pix);
  int mk = __builtin_nontemporal_load(maskp + pix);
  int e[5];
  #pragma unroll
  for (int l=0;l<5;l++) e[l] = __builtin_nontemporal_load(sp + pix*5 + l);
  dd = dd < 0 ? 0 : (dd > 5 ? 5 : dd);
  float b[8];
  #pragma unroll
  for (int x=0;x<8;x++) b[x] = sptab[dd*8 + x];
  #pragma unroll
  for (int l=0;l<5;l++){
    int ee = e[l];
    if ((unsigned)ee > (unsigned)NE) ee = NE;
    uint4 tv = *(const uint4*)(T2 + (size_t)ee*64 + l*8);
    b[0] += bf2f(tv.x & 0xffffu); b[1] += bf2f(tv.x >> 16);
    b[2] += bf2f(tv.y & 0xffffu); b[3] += bf2f(tv.y >> 16);
    b[4] += bf2f(tv.z & 0xffffu); b[5] += bf2f(tv.z >> 16);
    b[6] += bf2f(tv.w & 0xffffu); b[7] += bf2f(tv.w >> 16);
  }
  unsigned short o[8];
  #pragma unroll
  for (int x=0;x<8;x++) o[x] = mk ? f2bf(-1e30f) : f2bf(b[x]);
  u32x4 ov = *(const u32x4*)o;
  __builtin_nontemporal_store(ov, (u32x4*)(biasB + pix*8));
}

// ---------------- fused attention ----------------
// block = 512 threads = 8 waves, wave h owns head h.
// blockIdx.x = q-tile (16 queries), blockIdx.y = m-chunk (CHSZ keys = NJT tiles of 64).
// Softmax is over HEADS per (q,m) pair (reference uses axis=-1 on (n,m,h)!).
// All divergent gathers moved to bias_k; phase A is a coalesced 16B bias stream,
// register-prefetched one key-tile ahead.
__global__ __launch_bounds__(512) void attn_k(
    const unsigned short* __restrict__ Qb, const unsigned short* __restrict__ Kb,
    const unsigned short* __restrict__ Vt, const unsigned short* __restrict__ biasB,
    float* __restrict__ partO)
{
  __shared__ __attribute__((aligned(16))) float sld[NH][16][68];  // stride 68: 2-way aliasing only
  int tid = threadIdx.x;
  int lane = tid & 63, h = tid >> 6;
  int quad = lane >> 4, low = lane & 15;
  int q0 = blockIdx.x * 16;
  int chunk = blockIdx.y;

  bf16x8 aq[2];
  #pragma unroll
  for (int s=0;s<2;s++)
    aq[s] = *(const bf16x8*)(Qb + (size_t)(q0+low)*DIM + h*HD + s*32 + quad*8);

  f32x4 accO[4];
  #pragma unroll
  for (int t=0;t<4;t++) accO[t] = (f32x4){0.f,0.f,0.f,0.f};

  // prefetch first key-tile's bias (coalesced: consecutive tid -> consecutive 16B)
  uint4 pb[2];
  #pragma unroll
  for (int it=0; it<2; ++it){
    int p = tid + it*512;
    int qq = p >> 6, mm = p & 63;
    pb[it] = *(const uint4*)(biasB + ((size_t)(q0+qq)*NN + chunk*CHSZ + mm)*8);
  }

  for (int jt=0; jt<NJT; ++jt){
    int m0 = chunk*CHSZ + jt*64;
    __syncthreads();   // prior iteration's phase-D LDS readers done

    // ---- phase A: bias registers -> LDS ----
    #pragma unroll
    for (int it=0; it<2; ++it){
      int p = tid + it*512;
      int qq = p >> 6, mm = p & 63;
      uint4 tv = pb[it];
      sld[0][qq][mm] = bf2f(tv.x & 0xffffu); sld[1][qq][mm] = bf2f(tv.x >> 16);
      sld[2][qq][mm] = bf2f(tv.y & 0xffffu); sld[3][qq][mm] = bf2f(tv.y >> 16);
      sld[4][qq][mm] = bf2f(tv.z & 0xffffu); sld[5][qq][mm] = bf2f(tv.z >> 16);
      sld[6][qq][mm] = bf2f(tv.w & 0xffffu); sld[7][qq][mm] = bf2f(tv.w >> 16);
    }
    // issue next tile's bias loads (consumed next iteration)
    if (jt+1 < NJT){
      #pragma unroll
      for (int it=0; it<2; ++it){
        int p = tid + it*512;
        int qq = p >> 6, mm = p & 63;
        pb[it] = *(const uint4*)(biasB + ((size_t)(q0+qq)*NN + m0 + 64 + mm)*8);
      }
    }
    __syncthreads();

    // ---- phase B (wave h): S = Q K^T * 0.125 + bias, write back into own slice ----
    f32x4 S[4];
    #pragma unroll
    for (int t=0;t<4;t++) S[t] = (f32x4){0.f,0.f,0.f,0.f};
    #pragma unroll
    for (int s=0;s<2;s++){
      #pragma unroll
      for (int t=0;t<4;t++){
        bf16x8 bk = *(const bf16x8*)(Kb + (size_t)(m0+16*t+low)*DIM + h*HD + s*32 + quad*8);
        S[t] = MFMA(aq[s], bk, S[t]);
      }
    }
    #pragma unroll
    for (int t=0;t<4;t++){
      #pragma unroll
      for (int r=0;r<4;r++){
        float* slot = &sld[h][quad*4+r][low+16*t];
        *slot = S[t][r]*0.125f + *slot;
      }
    }
    __syncthreads();

    // ---- phase C (cooperative): softmax over the 8 heads per (q,m) pair ----
    #pragma unroll
    for (int it=0; it<2; ++it){
      int p = tid + it*512;
      int qq = p >> 6, mm = p & 63;
      float s0[8];
      #pragma unroll
      for (int x=0;x<8;x++) s0[x] = sld[x][qq][mm];
      float mx = s0[0];
      #pragma unroll
      for (int x=1;x<8;x++) mx = fmaxf(mx, s0[x]);
      float sum = 0.f;
      #pragma unroll
      for (int x=0;x<8;x++){ s0[x] = exp2f((s0[x]-mx)*LOG2E); sum += s0[x]; }
      float inv = (mx < -1e29f) ? 0.f : 1.f/sum;   // fully-masked pair -> zero weights
      #pragma unroll
      for (int x=0;x<8;x++) sld[x][qq][mm] = s0[x]*inv;
    }
    __syncthreads();

    // ---- phase D (wave h): O += P V ----
    bf16x8 ap[2];
    #pragma unroll
    for (int s=0;s<2;s++){
      const float* pp = &sld[h][low][s*32 + quad*8];
      float4 x0 = *(const float4*)pp;
      float4 x1 = *(const float4*)(pp + 4);
      bf16x8 a;
      a[0]=(short)f2bf(x0.x); a[1]=(short)f2bf(x0.y); a[2]=(short)f2bf(x0.z); a[3]=(short)f2bf(x0.w);
      a[4]=(short)f2bf(x1.x); a[5]=(short)f2bf(x1.y); a[6]=(short)f2bf(x1.z); a[7]=(short)f2bf(x1.w);
      ap[s] = a;
    }
    #pragma unroll
    for (int s=0;s<2;s++){
      #pragma unroll
      for (int t=0;t<4;t++){
        bf16x8 bv = *(const bf16x8*)(Vt + (size_t)(h*HD + 16*t + low)*NN + m0 + s*32 + quad*8);
        accO[t] = MFMA(ap[s], bv, accO[t]);
      }
    }
  }

  // ---- epilogue: per-chunk partial O (plain sum over m; no softmax state) ----
  #pragma unroll
  for (int t=0;t<4;t++){
    #pragma unroll
    for (int r=0;r<4;r++){
      int q = quad*4 + r;
      partO[(((size_t)chunk*NN + q0 + q)*NH + h)*HD + 16*t + low] = accO[t][r];
    }
  }
}

// ---------------- sum the CHUNKS partial O's, emit bf16 ----------------
__global__ __launch_bounds__(512) void merge_k(const float* __restrict__ partO,
                                               unsigned short* __restrict__ Obf)
{
  size_t idx = (size_t)blockIdx.x*512 + threadIdx.x;   // q*512 + h*64 + d
  float s = 0.f;
  #pragma unroll
  for (int c=0;c<CHUNKS;c++) s += partO[(size_t)c*NN*DIM + idx];
  Obf[idx] = f2bf(s);
}

extern "C" void kernel_launch(void* const* d_in, const int* in_sizes, int n_in,
                              void* d_out, int out_size, void* d_ws, size_t ws_size,
                              hipStream_t stream)
{
  const float* X    = (const float*)d_in[0];
  const int*  dist  = (const int*)d_in[3];
  const int*  sp    = (const int*)d_in[4];
  const float* ef   = (const float*)d_in[5];
  const int*  maskp = (const int*)d_in[6];
  const float* WQ   = (const float*)d_in[7];
  const float* bQ   = (const float*)d_in[8];
  const float* WK   = (const float*)d_in[9];
  const float* bK   = (const float*)d_in[10];
  const float* WV   = (const float*)d_in[11];
  const float* bV   = (const float*)d_in[12];
  const float* WO   = (const float*)d_in[13];
  const float* bO   = (const float*)d_in[14];
  const float* spb  = (const float*)d_in[15];
  const float* ew   = (const float*)d_in[16];

  char* ws = (char*)d_ws;
  unsigned short* Wt   = (unsigned short*)(ws + 0);            // 4 x 512x512 bf16 (Q,K,V,O transposed)
  unsigned short* Xb   = (unsigned short*)(ws + 2097152);      // 2048x512 bf16 node_feat
  unsigned short* Qb   = (unsigned short*)(ws + 4194304);      // 2048x512 bf16
  unsigned short* Kb   = (unsigned short*)(ws + 6291456);      // 2048x512 bf16
  unsigned short* Vtb  = (unsigned short*)(ws + 8388608);      // 512x2048 bf16 (transposed V)
  unsigned short* pEF  = (unsigned short*)(ws + 10485760);     // EPAD x 64 bf16
  unsigned short* pEW  = (unsigned short*)(ws + 14688256);     // 64 x 64 bf16
  unsigned short* T2   = (unsigned short*)(ws + 14696448);     // EPAD x 64 bf16: T2[e][l*8+h]
  unsigned short* Obf  = (unsigned short*)(ws + 18898944);     // 2048x512 bf16
  unsigned short* biasB= (unsigned short*)(ws + 20996096);     // NN x NN x 8 bf16 (67 MB)
  float*          pO   = (float*)(ws + 88104960);              // CHUNKS x 2048x512 f32 (16.8 MB; ws ~105 MB)

  cvt_k<<<dim3(1540), dim3(256), 0, stream>>>(X, ef, ew, Xb, pEF, pEW);
  transpose512<<<dim3(16,16,4), dim3(32,8), 0, stream>>>(WQ, WK, WV, WO, Wt);
  gemm_bt<<<dim3(2,513),  dim3(256), 0, stream>>>(pEF, pEW, (const float*)nullptr, T2, (float*)nullptr, EPAD, 64, 64, 0);
  bias_k<<<dim3(NN*NN/256), dim3(256), 0, stream>>>(T2, spb, dist, sp, maskp, biasB);
  gemm_bt<<<dim3(16,32),  dim3(256), 0, stream>>>(Xb,  Wt,          bQ, Qb,  (float*)nullptr, NN, DIM, DIM, 0);
  gemm_bt<<<dim3(16,32),  dim3(256), 0, stream>>>(Xb,  Wt + 262144, bK, Kb,  (float*)nullptr, NN, DIM, DIM, 0);
  gemm_bt<<<dim3(64,8),   dim3(256), 0, stream>>>(Wt + 524288, Xb,  bV, Vtb, (float*)nullptr, DIM, NN, DIM, 1);
  attn_k<<<dim3(128,CHUNKS), dim3(512), 0, stream>>>(Qb, Kb, Vtb, biasB, pO);
  merge_k<<<dim3(2048), dim3(512), 0, stream>>>(pO, Obf);
  gemm_bt<<<dim3(16,32), dim3(256), 0, stream>>>(Obf, Wt + 786432, bO, (unsigned short*)nullptr, (float*)d_out, NN, DIM, DIM, 0);
}

// Round 4
// 397.464 us; speedup vs baseline: 1.0740x; 1.0740x over previous
//
#include <hip/hip_runtime.h>

#define NN     2048
#define DIM    512
#define NH     8
#define HD     64
#define NE     32768
#define EPAD   32832
#define CHUNKS 4
#define CHSZ   (NN/CHUNKS)      /* 512 keys per chunk */
#define NJT    (CHSZ/64)        /* 8 key-tiles of 64 per chunk */
#define LOG2E  1.4426950408889634f

typedef __attribute__((ext_vector_type(8))) short bf16x8;
typedef __attribute__((ext_vector_type(4))) float f32x4;
typedef __attribute__((ext_vector_type(4))) unsigned int u32x4;

#define MFMA(a,b,c) __builtin_amdgcn_mfma_f32_16x16x32_bf16((a),(b),(c),0,0,0)

__device__ __forceinline__ float bf2f(unsigned int u16){
  union { unsigned int i; float f; } v; v.i = u16 << 16; return v.f;
}
__device__ __forceinline__ unsigned short f2bf(float f){
  union { float ff; unsigned int i; } v; v.ff = f;
  return (unsigned short)((v.i + 0x7fffu + ((v.i >> 16) & 1u)) >> 16);
}

// ------- fp32 -> bf16 staging: node_feat -> Xb, edge_feat -> pEF (pad rows NE..EPAD-1 = 0),
// ------- edge_weight -> pEW (64 rows, rows 40..63 = 0). One 8-elem group per thread.
__global__ __launch_bounds__(256) void cvt_k(
    const float* __restrict__ X, const float* __restrict__ ef, const float* __restrict__ ew,
    unsigned short* __restrict__ Xb, unsigned short* __restrict__ pEF, unsigned short* __restrict__ pEW)
{
  long g = (long)blockIdx.x*256 + threadIdx.x;   // 8-element group index
  const long GX = (long)NN*DIM/8;                // 131072 groups
  const long GE = (long)EPAD*8;                  // 262656 groups
  const float* src; unsigned short* dst; long off, lim8;
  if (g < GX){ src = X;  dst = Xb;  off = g;        lim8 = GX; }
  else if (g < GX+GE){ src = ef; dst = pEF; off = g-GX; lim8 = (long)NE*8; }
  else { off = g-GX-GE; if (off >= 512) return; src = ew; dst = pEW; lim8 = 320; }
  unsigned short o[8];
  if (off < lim8){
    #pragma unroll
    for (int i=0;i<8;i++) o[i] = f2bf(src[off*8+i]);
  } else {
    #pragma unroll
    for (int i=0;i<8;i++) o[i] = 0;
  }
  *(uint4*)(dst + off*8) = *(const uint4*)o;
}

// ---------------- transpose + convert four 512x512 fp32 weight matrices -> bf16 ----------------
__global__ __launch_bounds__(256) void transpose512(
    const float* __restrict__ a0, const float* __restrict__ a1,
    const float* __restrict__ a2, const float* __restrict__ a3,
    unsigned short* __restrict__ out)
{
  __shared__ unsigned short tile[32][33];
  const float* src = blockIdx.z==0 ? a0 : blockIdx.z==1 ? a1 : blockIdx.z==2 ? a2 : a3;
  unsigned short* dst = out + (size_t)blockIdx.z*DIM*DIM;
  int bx = blockIdx.x*32, by = blockIdx.y*32;
  int tx = threadIdx.x, ty = threadIdx.y;
  #pragma unroll
  for (int i=0;i<32;i+=8) tile[ty+i][tx] = f2bf(src[(size_t)(by+ty+i)*DIM + bx+tx]);
  __syncthreads();
  #pragma unroll
  for (int i=0;i<32;i+=8) dst[(size_t)(bx+ty+i)*DIM + by+tx] = tile[tx][ty+i];
}

// ---------------- generic C[M][N] = A1[M][K] * A2[N][K]^T + bias (final O-proj) ----------------
__global__ __launch_bounds__(256) void gemm_bt(
    const unsigned short* __restrict__ A1, const unsigned short* __restrict__ A2,
    const float* __restrict__ bias, unsigned short* __restrict__ C, float* __restrict__ Cf,
    int M, int N, int K, int bias_row)
{
  int lane = threadIdx.x & 63, w = threadIdx.x >> 6;
  int quad = lane >> 4, low = lane & 15;
  int m0 = blockIdx.y*64 + w*16;
  int n0 = blockIdx.x*32;
  f32x4 acc[2];
  acc[0] = (f32x4){0.f,0.f,0.f,0.f};
  acc[1] = (f32x4){0.f,0.f,0.f,0.f};
  #pragma unroll 4
  for (int k0=0; k0<K; k0+=32){
    bf16x8 a = *(const bf16x8*)(A1 + (size_t)(m0+low)*K + k0 + quad*8);
    #pragma unroll
    for (int t=0;t<2;t++){
      bf16x8 b = *(const bf16x8*)(A2 + (size_t)(n0+16*t+low)*K + k0 + quad*8);
      acc[t] = MFMA(a, b, acc[t]);
    }
  }
  #pragma unroll
  for (int t=0;t<2;t++){
    #pragma unroll
    for (int r=0;r<4;r++){
      int row = m0 + quad*4 + r;
      int col = n0 + 16*t + low;
      float v = acc[t][r];
      if (bias) v += bias[bias_row ? row : col];
      if (Cf) Cf[(size_t)row*N + col] = v;
      else    C [(size_t)row*N + col] = f2bf(v);
    }
  }
}

// ---------------- T2 gemm: T2L[l][e][h] = pEF[e]·pEW[l*8+h], per-l 16B rows ----------------
// Layout [8][EPAD][8] bf16: each l's gather window is 525KB -> hot set (l<5) 2.6MB, L2-resident.
__global__ __launch_bounds__(256) void gemm_t2(
    const unsigned short* __restrict__ A1, const unsigned short* __restrict__ A2,
    unsigned short* __restrict__ T2L)
{
  int lane = threadIdx.x & 63, w = threadIdx.x >> 6;
  int quad = lane >> 4, low = lane & 15;
  int m0 = blockIdx.y*64 + w*16;
  int n0 = blockIdx.x*32;
  f32x4 acc[2];
  acc[0] = (f32x4){0.f,0.f,0.f,0.f};
  acc[1] = (f32x4){0.f,0.f,0.f,0.f};
  #pragma unroll
  for (int k0=0; k0<64; k0+=32){
    bf16x8 a = *(const bf16x8*)(A1 + (size_t)(m0+low)*64 + k0 + quad*8);
    #pragma unroll
    for (int t=0;t<2;t++){
      bf16x8 b = *(const bf16x8*)(A2 + (size_t)(n0+16*t+low)*64 + k0 + quad*8);
      acc[t] = MFMA(a, b, acc[t]);
    }
  }
  #pragma unroll
  for (int t=0;t<2;t++){
    #pragma unroll
    for (int r=0;r<4;r++){
      int row = m0 + quad*4 + r;            // edge index
      int col = n0 + 16*t + low;            // l*8+h
      T2L[((size_t)(col>>3)*EPAD + row)*8 + (col&7)] = f2bf(acc[t][r]);
    }
  }
}

// ---------------- fused Q/K/V single-pass GEMM ----------------
// A-fragment (node_feat row) loaded ONCE feeds all three weight matrices; V written transposed.
__global__ __launch_bounds__(256) void qkv_k(
    const unsigned short* __restrict__ Xb, const unsigned short* __restrict__ Wt,
    const float* __restrict__ bQ, const float* __restrict__ bK, const float* __restrict__ bV,
    unsigned short* __restrict__ Qb, unsigned short* __restrict__ Kb, unsigned short* __restrict__ Vtb)
{
  int lane = threadIdx.x & 63, w = threadIdx.x >> 6;
  int quad = lane >> 4, low = lane & 15;
  int m0 = blockIdx.y*64 + w*16;          // node row
  int n0 = blockIdx.x*32;                 // output col
  f32x4 acc[3][2];
  #pragma unroll
  for (int z=0;z<3;z++){ acc[z][0]=(f32x4){0.f,0.f,0.f,0.f}; acc[z][1]=(f32x4){0.f,0.f,0.f,0.f}; }
  #pragma unroll 2
  for (int k0=0; k0<DIM; k0+=32){
    bf16x8 a = *(const bf16x8*)(Xb + (size_t)(m0+low)*DIM + k0 + quad*8);
    #pragma unroll
    for (int z=0;z<3;z++){
      #pragma unroll
      for (int t=0;t<2;t++){
        bf16x8 b = *(const bf16x8*)(Wt + (size_t)z*DIM*DIM + (size_t)(n0+16*t+low)*DIM + k0 + quad*8);
        acc[z][t] = MFMA(a, b, acc[z][t]);
      }
    }
  }
  #pragma unroll
  for (int t=0;t<2;t++){
    #pragma unroll
    for (int r=0;r<4;r++){
      int row = m0 + quad*4 + r;
      int col = n0 + 16*t + low;
      Qb[(size_t)row*DIM + col] = f2bf(acc[0][t][r] + bQ[col]);
      Kb[(size_t)row*DIM + col] = f2bf(acc[1][t][r] + bK[col]);
      Vtb[(size_t)col*NN + row] = f2bf(acc[2][t][r] + bV[col]);
    }
  }
}

// ---------------- dedicated bias-gather kernel ----------------
// bias[n][m][h] (bf16) = sp_table[dist][h] + sum_l T2L[l][sp_l][h], mask -> -1e30.
// Streams (dist/mask/sp) nontemporal; bias store CACHED so attn_k hits it in L2/L3.
__global__ __launch_bounds__(256) void bias_k(
    const unsigned short* __restrict__ T2L, const float* __restrict__ spb,
    const int* __restrict__ dist, const int* __restrict__ sp, const int* __restrict__ maskp,
    unsigned short* __restrict__ biasB)
{
  __shared__ float sptab[48];
  if (threadIdx.x < 48) sptab[threadIdx.x] = spb[threadIdx.x];
  __syncthreads();
  long pix = (long)blockIdx.x*256 + threadIdx.x;   // n*NN + m, grid covers NN*NN exactly
  int dd = __builtin_nontemporal_load(dist + pix);
  int mk = __builtin_nontemporal_load(maskp + pix);
  int e[5];
  #pragma unroll
  for (int l=0;l<5;l++) e[l] = __builtin_nontemporal_load(sp + pix*5 + l);
  dd = dd < 0 ? 0 : (dd > 5 ? 5 : dd);
  float b[8];
  #pragma unroll
  for (int x=0;x<8;x++) b[x] = sptab[dd*8 + x];
  #pragma unroll
  for (int l=0;l<5;l++){
    int ee = e[l];
    if ((unsigned)ee > (unsigned)NE) ee = NE;
    uint4 tv = *(const uint4*)(T2L + ((size_t)l*EPAD + ee)*8);
    b[0] += bf2f(tv.x & 0xffffu); b[1] += bf2f(tv.x >> 16);
    b[2] += bf2f(tv.y & 0xffffu); b[3] += bf2f(tv.y >> 16);
    b[4] += bf2f(tv.z & 0xffffu); b[5] += bf2f(tv.z >> 16);
    b[6] += bf2f(tv.w & 0xffffu); b[7] += bf2f(tv.w >> 16);
  }
  unsigned short o[8];
  #pragma unroll
  for (int x=0;x<8;x++) o[x] = mk ? f2bf(-1e30f) : f2bf(b[x]);
  *(uint4*)(biasB + pix*8) = *(const uint4*)o;
}

// ---------------- fused attention ----------------
// block = 512 threads = 8 waves, wave h owns head h.
// blockIdx.x = q-tile (16 queries), blockIdx.y = m-chunk (CHSZ keys = NJT tiles of 64).
// Softmax is over HEADS per (q,m) pair (reference uses axis=-1 on (n,m,h)!).
__global__ __launch_bounds__(512) void attn_k(
    const unsigned short* __restrict__ Qb, const unsigned short* __restrict__ Kb,
    const unsigned short* __restrict__ Vt, const unsigned short* __restrict__ biasB,
    float* __restrict__ partO)
{
  __shared__ __attribute__((aligned(16))) float sld[NH][16][68];  // stride 68: 2-way aliasing only
  int tid = threadIdx.x;
  int lane = tid & 63, h = tid >> 6;
  int quad = lane >> 4, low = lane & 15;
  int q0 = blockIdx.x * 16;
  int chunk = blockIdx.y;

  bf16x8 aq[2];
  #pragma unroll
  for (int s=0;s<2;s++)
    aq[s] = *(const bf16x8*)(Qb + (size_t)(q0+low)*DIM + h*HD + s*32 + quad*8);

  f32x4 accO[4];
  #pragma unroll
  for (int t=0;t<4;t++) accO[t] = (f32x4){0.f,0.f,0.f,0.f};

  // prefetch first key-tile's bias (coalesced: consecutive tid -> consecutive 16B)
  uint4 pb[2];
  #pragma unroll
  for (int it=0; it<2; ++it){
    int p = tid + it*512;
    int qq = p >> 6, mm = p & 63;
    pb[it] = *(const uint4*)(biasB + ((size_t)(q0+qq)*NN + chunk*CHSZ + mm)*8);
  }

  for (int jt=0; jt<NJT; ++jt){
    int m0 = chunk*CHSZ + jt*64;
    __syncthreads();   // prior iteration's phase-D LDS readers done

    // ---- phase A: bias registers -> LDS ----
    #pragma unroll
    for (int it=0; it<2; ++it){
      int p = tid + it*512;
      int qq = p >> 6, mm = p & 63;
      uint4 tv = pb[it];
      sld[0][qq][mm] = bf2f(tv.x & 0xffffu); sld[1][qq][mm] = bf2f(tv.x >> 16);
      sld[2][qq][mm] = bf2f(tv.y & 0xffffu); sld[3][qq][mm] = bf2f(tv.y >> 16);
      sld[4][qq][mm] = bf2f(tv.z & 0xffffu); sld[5][qq][mm] = bf2f(tv.z >> 16);
      sld[6][qq][mm] = bf2f(tv.w & 0xffffu); sld[7][qq][mm] = bf2f(tv.w >> 16);
    }
    // issue next tile's bias loads (consumed next iteration)
    if (jt+1 < NJT){
      #pragma unroll
      for (int it=0; it<2; ++it){
        int p = tid + it*512;
        int qq = p >> 6, mm = p & 63;
        pb[it] = *(const uint4*)(biasB + ((size_t)(q0+qq)*NN + m0 + 64 + mm)*8);
      }
    }
    __syncthreads();

    // ---- phase B (wave h): S = Q K^T * 0.125 + bias, write back into own slice ----
    f32x4 S[4];
    #pragma unroll
    for (int t=0;t<4;t++) S[t] = (f32x4){0.f,0.f,0.f,0.f};
    #pragma unroll
    for (int s=0;s<2;s++){
      #pragma unroll
      for (int t=0;t<4;t++){
        bf16x8 bk = *(const bf16x8*)(Kb + (size_t)(m0+16*t+low)*DIM + h*HD + s*32 + quad*8);
        S[t] = MFMA(aq[s], bk, S[t]);
      }
    }
    #pragma unroll
    for (int t=0;t<4;t++){
      #pragma unroll
      for (int r=0;r<4;r++){
        float* slot = &sld[h][quad*4+r][low+16*t];
        *slot = S[t][r]*0.125f + *slot;
      }
    }
    __syncthreads();

    // ---- phase C (cooperative): softmax over the 8 heads per (q,m) pair ----
    #pragma unroll
    for (int it=0; it<2; ++it){
      int p = tid + it*512;
      int qq = p >> 6, mm = p & 63;
      float s0[8];
      #pragma unroll
      for (int x=0;x<8;x++) s0[x] = sld[x][qq][mm];
      float mx = s0[0];
      #pragma unroll
      for (int x=1;x<8;x++) mx = fmaxf(mx, s0[x]);
      float sum = 0.f;
      #pragma unroll
      for (int x=0;x<8;x++){ s0[x] = exp2f((s0[x]-mx)*LOG2E); sum += s0[x]; }
      float inv = (mx < -1e29f) ? 0.f : 1.f/sum;   // fully-masked pair -> zero weights
      #pragma unroll
      for (int x=0;x<8;x++) sld[x][qq][mm] = s0[x]*inv;
    }
    __syncthreads();

    // ---- phase D (wave h): O += P V ----
    bf16x8 ap[2];
    #pragma unroll
    for (int s=0;s<2;s++){
      const float* pp = &sld[h][low][s*32 + quad*8];
      float4 x0 = *(const float4*)pp;
      float4 x1 = *(const float4*)(pp + 4);
      bf16x8 a;
      a[0]=(short)f2bf(x0.x); a[1]=(short)f2bf(x0.y); a[2]=(short)f2bf(x0.z); a[3]=(short)f2bf(x0.w);
      a[4]=(short)f2bf(x1.x); a[5]=(short)f2bf(x1.y); a[6]=(short)f2bf(x1.z); a[7]=(short)f2bf(x1.w);
      ap[s] = a;
    }
    #pragma unroll
    for (int s=0;s<2;s++){
      #pragma unroll
      for (int t=0;t<4;t++){
        bf16x8 bv = *(const bf16x8*)(Vt + (size_t)(h*HD + 16*t + low)*NN + m0 + s*32 + quad*8);
        accO[t] = MFMA(ap[s], bv, accO[t]);
      }
    }
  }

  // ---- epilogue: per-chunk partial O (plain sum over m; no softmax state) ----
  #pragma unroll
  for (int t=0;t<4;t++){
    #pragma unroll
    for (int r=0;r<4;r++){
      int q = quad*4 + r;
      partO[(((size_t)chunk*NN + q0 + q)*NH + h)*HD + 16*t + low] = accO[t][r];
    }
  }
}

// ---------------- sum the CHUNKS partial O's, emit bf16 ----------------
__global__ __launch_bounds__(512) void merge_k(const float* __restrict__ partO,
                                               unsigned short* __restrict__ Obf)
{
  size_t idx = (size_t)blockIdx.x*512 + threadIdx.x;   // q*512 + h*64 + d
  float s = 0.f;
  #pragma unroll
  for (int c=0;c<CHUNKS;c++) s += partO[(size_t)c*NN*DIM + idx];
  Obf[idx] = f2bf(s);
}

extern "C" void kernel_launch(void* const* d_in, const int* in_sizes, int n_in,
                              void* d_out, int out_size, void* d_ws, size_t ws_size,
                              hipStream_t stream)
{
  const float* X    = (const float*)d_in[0];
  const int*  dist  = (const int*)d_in[3];
  const int*  sp    = (const int*)d_in[4];
  const float* ef   = (const float*)d_in[5];
  const int*  maskp = (const int*)d_in[6];
  const float* WQ   = (const float*)d_in[7];
  const float* bQ   = (const float*)d_in[8];
  const float* WK   = (const float*)d_in[9];
  const float* bK   = (const float*)d_in[10];
  const float* WV   = (const float*)d_in[11];
  const float* bV   = (const float*)d_in[12];
  const float* WO   = (const float*)d_in[13];
  const float* bO   = (const float*)d_in[14];
  const float* spb  = (const float*)d_in[15];
  const float* ew   = (const float*)d_in[16];

  char* ws = (char*)d_ws;
  unsigned short* Wt   = (unsigned short*)(ws + 0);            // 4 x 512x512 bf16 (Q,K,V,O transposed)
  unsigned short* Xb   = (unsigned short*)(ws + 2097152);      // 2048x512 bf16 node_feat
  unsigned short* Qb   = (unsigned short*)(ws + 4194304);      // 2048x512 bf16
  unsigned short* Kb   = (unsigned short*)(ws + 6291456);      // 2048x512 bf16
  unsigned short* Vtb  = (unsigned short*)(ws + 8388608);      // 512x2048 bf16 (transposed V)
  unsigned short* pEF  = (unsigned short*)(ws + 10485760);     // EPAD x 64 bf16
  unsigned short* pEW  = (unsigned short*)(ws + 14688256);     // 64 x 64 bf16
  unsigned short* T2L  = (unsigned short*)(ws + 14696448);     // [8][EPAD][8] bf16 per-l rows (4.2MB)
  unsigned short* Obf  = (unsigned short*)(ws + 18898944);     // 2048x512 bf16
  unsigned short* biasB= (unsigned short*)(ws + 20996096);     // NN x NN x 8 bf16 (67 MB)
  float*          pO   = (float*)(ws + 88104960);              // CHUNKS x 2048x512 f32 (16.8 MB; ws ~105 MB)

  cvt_k<<<dim3(1540), dim3(256), 0, stream>>>(X, ef, ew, Xb, pEF, pEW);
  transpose512<<<dim3(16,16,4), dim3(32,8), 0, stream>>>(WQ, WK, WV, WO, Wt);
  gemm_t2<<<dim3(2,513), dim3(256), 0, stream>>>(pEF, pEW, T2L);
  bias_k<<<dim3(NN*NN/256), dim3(256), 0, stream>>>(T2L, spb, dist, sp, maskp, biasB);
  qkv_k<<<dim3(16,32), dim3(256), 0, stream>>>(Xb, Wt, bQ, bK, bV, Qb, Kb, Vtb);
  attn_k<<<dim3(128,CHUNKS), dim3(512), 0, stream>>>(Qb, Kb, Vtb, biasB, pO);
  merge_k<<<dim3(2048), dim3(512), 0, stream>>>(pO, Obf);
  gemm_bt<<<dim3(16,32), dim3(256), 0, stream>>>(Obf, Wt + 786432, bO, (unsigned short*)nullptr, (float*)d_out, NN, DIM, DIM, 0);
}

// Round 5
// 371.565 us; speedup vs baseline: 1.1489x; 1.0697x over previous
//
#include <hip/hip_runtime.h>

#define NN     2048
#define DIM    512
#define NH     8
#define HD     64
#define NE     32768
#define EPAD   32832
#define CHUNKS 8
#define CHSZ   (NN/CHUNKS)      /* 256 keys per chunk */
#define NJT    (CHSZ/64)        /* 4 key-tiles of 64 per chunk */
#define QBLK   32
#define LOG2E  1.4426950408889634f

typedef __attribute__((ext_vector_type(8))) short bf16x8;
typedef __attribute__((ext_vector_type(4))) float f32x4;
typedef __attribute__((ext_vector_type(4))) unsigned int u32x4;

#define MFMA(a,b,c) __builtin_amdgcn_mfma_f32_16x16x32_bf16((a),(b),(c),0,0,0)

__device__ __forceinline__ float bf2f(unsigned int u16){
  union { unsigned int i; float f; } v; v.i = u16 << 16; return v.f;
}
__device__ __forceinline__ unsigned short f2bf(float f){
  union { float ff; unsigned int i; } v; v.ff = f;
  return (unsigned short)((v.i + 0x7fffu + ((v.i >> 16) & 1u)) >> 16);
}

// ---------------- fused prep: cvt (blocks 0..1539) + weight transpose (blocks 1540..2563) ----------------
__global__ __launch_bounds__(256) void prep_k(
    const float* __restrict__ X, const float* __restrict__ ef, const float* __restrict__ ew,
    unsigned short* __restrict__ Xb, unsigned short* __restrict__ pEF, unsigned short* __restrict__ pEW,
    const float* __restrict__ a0, const float* __restrict__ a1,
    const float* __restrict__ a2, const float* __restrict__ a3,
    unsigned short* __restrict__ Wt)
{
  __shared__ unsigned short tile[32][33];
  if (blockIdx.x < 1540){
    long g = (long)blockIdx.x*256 + threadIdx.x;   // 8-element group index
    const long GX = (long)NN*DIM/8;                // 131072 groups
    const long GE = (long)EPAD*8;                  // 262656 groups
    const float* src; unsigned short* dst; long off, lim8;
    if (g < GX){ src = X;  dst = Xb;  off = g;        lim8 = GX; }
    else if (g < GX+GE){ src = ef; dst = pEF; off = g-GX; lim8 = (long)NE*8; }
    else { off = g-GX-GE; if (off >= 512) return; src = ew; dst = pEW; lim8 = 320; }
    unsigned short o[8];
    if (off < lim8){
      #pragma unroll
      for (int i=0;i<8;i++) o[i] = f2bf(src[off*8+i]);
    } else {
      #pragma unroll
      for (int i=0;i<8;i++) o[i] = 0;
    }
    *(uint4*)(dst + off*8) = *(const uint4*)o;
  } else {
    int b2 = blockIdx.x - 1540;                    // 0..1023
    int bz = b2 >> 8, rem = b2 & 255;
    int bx = (rem & 15)*32, by = (rem >> 4)*32;
    int tx = threadIdx.x & 31, ty = threadIdx.x >> 5;
    const float* src = bz==0 ? a0 : bz==1 ? a1 : bz==2 ? a2 : a3;
    unsigned short* dst = Wt + (size_t)bz*DIM*DIM;
    #pragma unroll
    for (int i=0;i<32;i+=8) tile[ty+i][tx] = f2bf(src[(size_t)(by+ty+i)*DIM + bx+tx]);
    __syncthreads();
    #pragma unroll
    for (int i=0;i<32;i+=8) dst[(size_t)(bx+ty+i)*DIM + by+tx] = tile[tx][ty+i];
  }
}

// ---------------- generic C[M][N] = A1[M][K] * A2[N][K]^T + bias (final O-proj) ----------------
__global__ __launch_bounds__(256) void gemm_bt(
    const unsigned short* __restrict__ A1, const unsigned short* __restrict__ A2,
    const float* __restrict__ bias, unsigned short* __restrict__ C, float* __restrict__ Cf,
    int M, int N, int K, int bias_row)
{
  int lane = threadIdx.x & 63, w = threadIdx.x >> 6;
  int quad = lane >> 4, low = lane & 15;
  int m0 = blockIdx.y*64 + w*16;
  int n0 = blockIdx.x*32;
  f32x4 acc[2];
  acc[0] = (f32x4){0.f,0.f,0.f,0.f};
  acc[1] = (f32x4){0.f,0.f,0.f,0.f};
  #pragma unroll 4
  for (int k0=0; k0<K; k0+=32){
    bf16x8 a = *(const bf16x8*)(A1 + (size_t)(m0+low)*K + k0 + quad*8);
    #pragma unroll
    for (int t=0;t<2;t++){
      bf16x8 b = *(const bf16x8*)(A2 + (size_t)(n0+16*t+low)*K + k0 + quad*8);
      acc[t] = MFMA(a, b, acc[t]);
    }
  }
  #pragma unroll
  for (int t=0;t<2;t++){
    #pragma unroll
    for (int r=0;r<4;r++){
      int row = m0 + quad*4 + r;
      int col = n0 + 16*t + low;
      float v = acc[t][r];
      if (bias) v += bias[bias_row ? row : col];
      if (Cf) Cf[(size_t)row*N + col] = v;
      else    C [(size_t)row*N + col] = f2bf(v);
    }
  }
}

// ---------------- T2 gemm: T2L[l][e][h] = pEF[e]·pEW[l*8+h], per-l 16B rows ----------------
// Layout [8][EPAD][8] bf16: each l's gather window is 525KB -> hot set (l<5) 2.6MB, L2-resident.
__global__ __launch_bounds__(256) void gemm_t2(
    const unsigned short* __restrict__ A1, const unsigned short* __restrict__ A2,
    unsigned short* __restrict__ T2L)
{
  int lane = threadIdx.x & 63, w = threadIdx.x >> 6;
  int quad = lane >> 4, low = lane & 15;
  int m0 = blockIdx.y*64 + w*16;
  int n0 = blockIdx.x*32;
  f32x4 acc[2];
  acc[0] = (f32x4){0.f,0.f,0.f,0.f};
  acc[1] = (f32x4){0.f,0.f,0.f,0.f};
  #pragma unroll
  for (int k0=0; k0<64; k0+=32){
    bf16x8 a = *(const bf16x8*)(A1 + (size_t)(m0+low)*64 + k0 + quad*8);
    #pragma unroll
    for (int t=0;t<2;t++){
      bf16x8 b = *(const bf16x8*)(A2 + (size_t)(n0+16*t+low)*64 + k0 + quad*8);
      acc[t] = MFMA(a, b, acc[t]);
    }
  }
  #pragma unroll
  for (int t=0;t<2;t++){
    #pragma unroll
    for (int r=0;r<4;r++){
      int row = m0 + quad*4 + r;            // edge index
      int col = n0 + 16*t + low;            // l*8+h
      T2L[((size_t)(col>>3)*EPAD + row)*8 + (col&7)] = f2bf(acc[t][r]);
    }
  }
}

// ---------------- co-scheduled bias-gather + fused QKV GEMM ----------------
// blocks 0..511: QKV (MFMA-bound, launched first so they start immediately);
// blocks 512..16895: bias gather (L2-request-bound). Disjoint pipes -> overlap.
__global__ __launch_bounds__(256) void biasqkv_k(
    const unsigned short* __restrict__ T2L, const float* __restrict__ spb,
    const int* __restrict__ dist, const int* __restrict__ sp, const int* __restrict__ maskp,
    unsigned short* __restrict__ biasB,
    const unsigned short* __restrict__ Xb, const unsigned short* __restrict__ Wt,
    const float* __restrict__ bQ, const float* __restrict__ bK, const float* __restrict__ bV,
    unsigned short* __restrict__ Qb, unsigned short* __restrict__ Kb, unsigned short* __restrict__ Vtb)
{
  __shared__ float sptab[48];
  if (blockIdx.x >= 512){
    // ---------- bias gather ----------
    if (threadIdx.x < 48) sptab[threadIdx.x] = spb[threadIdx.x];
    __syncthreads();
    long pix = (long)(blockIdx.x - 512)*256 + threadIdx.x;   // n*NN + m, covers NN*NN
    int dd = __builtin_nontemporal_load(dist + pix);
    int mk = __builtin_nontemporal_load(maskp + pix);
    int e[5];
    #pragma unroll
    for (int l=0;l<5;l++) e[l] = __builtin_nontemporal_load(sp + pix*5 + l);
    dd = dd < 0 ? 0 : (dd > 5 ? 5 : dd);
    float b[8];
    #pragma unroll
    for (int x=0;x<8;x++) b[x] = sptab[dd*8 + x];
    #pragma unroll
    for (int l=0;l<5;l++){
      int ee = e[l];
      if ((unsigned)ee > (unsigned)NE) ee = NE;
      uint4 tv = *(const uint4*)(T2L + ((size_t)l*EPAD + ee)*8);
      b[0] += bf2f(tv.x & 0xffffu); b[1] += bf2f(tv.x >> 16);
      b[2] += bf2f(tv.y & 0xffffu); b[3] += bf2f(tv.y >> 16);
      b[4] += bf2f(tv.z & 0xffffu); b[5] += bf2f(tv.z >> 16);
      b[6] += bf2f(tv.w & 0xffffu); b[7] += bf2f(tv.w >> 16);
    }
    unsigned short o[8];
    #pragma unroll
    for (int x=0;x<8;x++) o[x] = mk ? f2bf(-1e30f) : f2bf(b[x]);
    *(uint4*)(biasB + pix*8) = *(const uint4*)o;
  } else {
    // ---------- fused Q/K/V GEMM: A-fragment loaded once feeds 3 weights ----------
    int bid = blockIdx.x;                  // 0..511 -> (bx 0..15, by 0..31)
    int lane = threadIdx.x & 63, w = threadIdx.x >> 6;
    int quad = lane >> 4, low = lane & 15;
    int m0 = (bid >> 4)*64 + w*16;         // node row
    int n0 = (bid & 15)*32;                // output col
    f32x4 acc[3][2];
    #pragma unroll
    for (int z=0;z<3;z++){ acc[z][0]=(f32x4){0.f,0.f,0.f,0.f}; acc[z][1]=(f32x4){0.f,0.f,0.f,0.f}; }
    #pragma unroll 2
    for (int k0=0; k0<DIM; k0+=32){
      bf16x8 a = *(const bf16x8*)(Xb + (size_t)(m0+low)*DIM + k0 + quad*8);
      #pragma unroll
      for (int z=0;z<3;z++){
        #pragma unroll
        for (int t=0;t<2;t++){
          bf16x8 b = *(const bf16x8*)(Wt + (size_t)z*DIM*DIM + (size_t)(n0+16*t+low)*DIM + k0 + quad*8);
          acc[z][t] = MFMA(a, b, acc[z][t]);
        }
      }
    }
    #pragma unroll
    for (int t=0;t<2;t++){
      #pragma unroll
      for (int r=0;r<4;r++){
        int row = m0 + quad*4 + r;
        int col = n0 + 16*t + low;
        Qb[(size_t)row*DIM + col] = f2bf(acc[0][t][r] + bQ[col]);
        Kb[(size_t)row*DIM + col] = f2bf(acc[1][t][r] + bK[col]);
        Vtb[(size_t)col*NN + row] = f2bf(acc[2][t][r] + bV[col]);
      }
    }
  }
}

// ---------------- fused attention ----------------
// block = 512 threads = 8 waves, wave h owns head h. QBLK=32 queries per block
// (halves K/V cache traffic vs 16). blockIdx.x = q-tile, blockIdx.y = m-chunk.
// Softmax is over HEADS per (q,m) pair (reference uses axis=-1 on (n,m,h)!).
__global__ __launch_bounds__(512, 4) void attn_k(
    const unsigned short* __restrict__ Qb, const unsigned short* __restrict__ Kb,
    const unsigned short* __restrict__ Vt, const unsigned short* __restrict__ biasB,
    float* __restrict__ partO)
{
  __shared__ __attribute__((aligned(16))) float sld[NH][QBLK][68];  // 69.6 KB -> 2 blocks/CU
  int tid = threadIdx.x;
  int lane = tid & 63, h = tid >> 6;
  int quad = lane >> 4, low = lane & 15;
  int q0 = blockIdx.x * QBLK;
  int chunk = blockIdx.y;

  bf16x8 aq[2][2];
  #pragma unroll
  for (int sq=0;sq<2;sq++)
    #pragma unroll
    for (int s=0;s<2;s++)
      aq[sq][s] = *(const bf16x8*)(Qb + (size_t)(q0+sq*16+low)*DIM + h*HD + s*32 + quad*8);

  f32x4 accO[2][4];
  #pragma unroll
  for (int sq=0;sq<2;sq++)
    #pragma unroll
    for (int t=0;t<4;t++) accO[sq][t] = (f32x4){0.f,0.f,0.f,0.f};

  // prefetch first key-tile's bias (coalesced: consecutive tid -> consecutive 16B)
  uint4 pb[4];
  #pragma unroll
  for (int it=0; it<4; ++it){
    int p = tid + it*512;
    int qq = p >> 6, mm = p & 63;
    pb[it] = *(const uint4*)(biasB + ((size_t)(q0+qq)*NN + chunk*CHSZ + mm)*8);
  }

  for (int jt=0; jt<NJT; ++jt){
    int m0 = chunk*CHSZ + jt*64;
    __syncthreads();   // prior iteration's phase-D LDS readers done

    // ---- phase A: bias registers -> LDS ----
    #pragma unroll
    for (int it=0; it<4; ++it){
      int p = tid + it*512;
      int qq = p >> 6, mm = p & 63;
      uint4 tv = pb[it];
      sld[0][qq][mm] = bf2f(tv.x & 0xffffu); sld[1][qq][mm] = bf2f(tv.x >> 16);
      sld[2][qq][mm] = bf2f(tv.y & 0xffffu); sld[3][qq][mm] = bf2f(tv.y >> 16);
      sld[4][qq][mm] = bf2f(tv.z & 0xffffu); sld[5][qq][mm] = bf2f(tv.z >> 16);
      sld[6][qq][mm] = bf2f(tv.w & 0xffffu); sld[7][qq][mm] = bf2f(tv.w >> 16);
    }
    // issue next tile's bias loads (consumed next iteration)
    if (jt+1 < NJT){
      #pragma unroll
      for (int it=0; it<4; ++it){
        int p = tid + it*512;
        int qq = p >> 6, mm = p & 63;
        pb[it] = *(const uint4*)(biasB + ((size_t)(q0+qq)*NN + m0 + 64 + mm)*8);
      }
    }
    __syncthreads();

    // ---- phase B (wave h): S = Q K^T * 0.125 + bias, write back into own slice ----
    f32x4 S[2][4];
    #pragma unroll
    for (int sq=0;sq<2;sq++)
      #pragma unroll
      for (int t=0;t<4;t++) S[sq][t] = (f32x4){0.f,0.f,0.f,0.f};
    #pragma unroll
    for (int s=0;s<2;s++){
      #pragma unroll
      for (int t=0;t<4;t++){
        bf16x8 bk = *(const bf16x8*)(Kb + (size_t)(m0+16*t+low)*DIM + h*HD + s*32 + quad*8);
        #pragma unroll
        for (int sq=0;sq<2;sq++)
          S[sq][t] = MFMA(aq[sq][s], bk, S[sq][t]);
      }
    }
    #pragma unroll
    for (int sq=0;sq<2;sq++){
      #pragma unroll
      for (int t=0;t<4;t++){
        #pragma unroll
        for (int r=0;r<4;r++){
          float* slot = &sld[h][sq*16+quad*4+r][low+16*t];
          *slot = S[sq][t][r]*0.125f + *slot;
        }
      }
    }
    __syncthreads();

    // ---- phase C (cooperative): softmax over the 8 heads per (q,m) pair ----
    #pragma unroll
    for (int it=0; it<4; ++it){
      int p = tid + it*512;
      int qq = p >> 6, mm = p & 63;
      float s0[8];
      #pragma unroll
      for (int x=0;x<8;x++) s0[x] = sld[x][qq][mm];
      float mx = s0[0];
      #pragma unroll
      for (int x=1;x<8;x++) mx = fmaxf(mx, s0[x]);
      float sum = 0.f;
      #pragma unroll
      for (int x=0;x<8;x++){ s0[x] = exp2f((s0[x]-mx)*LOG2E); sum += s0[x]; }
      float inv = (mx < -1e29f) ? 0.f : 1.f/sum;   // fully-masked pair -> zero weights
      #pragma unroll
      for (int x=0;x<8;x++) sld[x][qq][mm] = s0[x]*inv;
    }
    __syncthreads();

    // ---- phase D (wave h): O += P V ----
    bf16x8 ap[2][2];
    #pragma unroll
    for (int sq=0;sq<2;sq++){
      #pragma unroll
      for (int s=0;s<2;s++){
        const float* pp = &sld[h][sq*16+low][s*32 + quad*8];
        float4 x0 = *(const float4*)pp;
        float4 x1 = *(const float4*)(pp + 4);
        bf16x8 a;
        a[0]=(short)f2bf(x0.x); a[1]=(short)f2bf(x0.y); a[2]=(short)f2bf(x0.z); a[3]=(short)f2bf(x0.w);
        a[4]=(short)f2bf(x1.x); a[5]=(short)f2bf(x1.y); a[6]=(short)f2bf(x1.z); a[7]=(short)f2bf(x1.w);
        ap[sq][s] = a;
      }
    }
    #pragma unroll
    for (int s=0;s<2;s++){
      #pragma unroll
      for (int t=0;t<4;t++){
        bf16x8 bv = *(const bf16x8*)(Vt + (size_t)(h*HD + 16*t + low)*NN + m0 + s*32 + quad*8);
        #pragma unroll
        for (int sq=0;sq<2;sq++)
          accO[sq][t] = MFMA(ap[sq][s], bv, accO[sq][t]);
      }
    }
  }

  // ---- epilogue: per-chunk partial O (plain sum over m; no softmax state) ----
  #pragma unroll
  for (int sq=0;sq<2;sq++){
    #pragma unroll
    for (int t=0;t<4;t++){
      #pragma unroll
      for (int r=0;r<4;r++){
        int q = sq*16 + quad*4 + r;
        partO[(((size_t)chunk*NN + q0 + q)*NH + h)*HD + 16*t + low] = accO[sq][t][r];
      }
    }
  }
}

// ---------------- sum the CHUNKS partial O's, emit bf16 ----------------
__global__ __launch_bounds__(512) void merge_k(const float* __restrict__ partO,
                                               unsigned short* __restrict__ Obf)
{
  size_t idx = (size_t)blockIdx.x*512 + threadIdx.x;   // q*512 + h*64 + d
  float s = 0.f;
  #pragma unroll
  for (int c=0;c<CHUNKS;c++) s += partO[(size_t)c*NN*DIM + idx];
  Obf[idx] = f2bf(s);
}

extern "C" void kernel_launch(void* const* d_in, const int* in_sizes, int n_in,
                              void* d_out, int out_size, void* d_ws, size_t ws_size,
                              hipStream_t stream)
{
  const float* X    = (const float*)d_in[0];
  const int*  dist  = (const int*)d_in[3];
  const int*  sp    = (const int*)d_in[4];
  const float* ef   = (const float*)d_in[5];
  const int*  maskp = (const int*)d_in[6];
  const float* WQ   = (const float*)d_in[7];
  const float* bQ   = (const float*)d_in[8];
  const float* WK   = (const float*)d_in[9];
  const float* bK   = (const float*)d_in[10];
  const float* WV   = (const float*)d_in[11];
  const float* bV   = (const float*)d_in[12];
  const float* WO   = (const float*)d_in[13];
  const float* bO   = (const float*)d_in[14];
  const float* spb  = (const float*)d_in[15];
  const float* ew   = (const float*)d_in[16];

  char* ws = (char*)d_ws;
  unsigned short* Wt   = (unsigned short*)(ws + 0);            // 4 x 512x512 bf16 (Q,K,V,O transposed)
  unsigned short* Xb   = (unsigned short*)(ws + 2097152);      // 2048x512 bf16 node_feat
  unsigned short* Qb   = (unsigned short*)(ws + 4194304);      // 2048x512 bf16
  unsigned short* Kb   = (unsigned short*)(ws + 6291456);      // 2048x512 bf16
  unsigned short* Vtb  = (unsigned short*)(ws + 8388608);      // 512x2048 bf16 (transposed V)
  unsigned short* pEF  = (unsigned short*)(ws + 10485760);     // EPAD x 64 bf16
  unsigned short* pEW  = (unsigned short*)(ws + 14688256);     // 64 x 64 bf16
  unsigned short* T2L  = (unsigned short*)(ws + 14696448);     // [8][EPAD][8] bf16 per-l rows (4.2MB)
  unsigned short* Obf  = (unsigned short*)(ws + 18898944);     // 2048x512 bf16
  unsigned short* biasB= (unsigned short*)(ws + 20996096);     // NN x NN x 8 bf16 (67 MB)
  float*          pO   = (float*)(ws + 88104960);              // CHUNKS x 2048x512 f32 (33.5 MB; ws ~122 MB)

  prep_k<<<dim3(2564), dim3(256), 0, stream>>>(X, ef, ew, Xb, pEF, pEW, WQ, WK, WV, WO, Wt);
  gemm_t2<<<dim3(2,513), dim3(256), 0, stream>>>(pEF, pEW, T2L);
  biasqkv_k<<<dim3(512 + NN*NN/256), dim3(256), 0, stream>>>(
      T2L, spb, dist, sp, maskp, biasB, Xb, Wt, bQ, bK, bV, Qb, Kb, Vtb);
  attn_k<<<dim3(NN/QBLK, CHUNKS), dim3(512), 0, stream>>>(Qb, Kb, Vtb, biasB, pO);
  merge_k<<<dim3(2048), dim3(512), 0, stream>>>(pO, Obf);
  gemm_bt<<<dim3(16,32), dim3(256), 0, stream>>>(Obf, Wt + 786432, bO, (unsigned short*)nullptr, (float*)d_out, NN, DIM, DIM, 0);
}